// Round 1
// baseline (2916.306 us; speedup 1.0000x reference)
//
#include <hip/hip_runtime.h>
#include <math.h>

#define NN 100000
#define NE 1250000
#define EPSI 1e-5f

// ---- workspace layout (bytes) ----
#define WS_W        0ull          // bf16 [NE*64]            160,000,000
#define WS_AGG      160000000ull  // f32  [NN*64]             25,600,000
#define WS_GI       185600000ull  // bf16 [192*NN]            38,400,000
#define WS_GH       224000000ull  // bf16 [192*NN]            38,400,000
#define WS_STATS    262400000ull  // f32x4 [NN]                1,600,000
#define WS_INVDEG   264000000ull  // f32 [NN]                    400,000
#define WS_COUNTS   264400000ull  // i32 [NN]                    400,000
#define WS_ROWSTART 264800000ull  // i32 [NN+1]
#define WS_CURSOR   265200128ull  // i32 [NN]
#define WS_BSUM     265600128ull  // i32 [391]
#define WS_BSUMEX   265601792ull  // i32 [391]
#define WS_REC      265603584ull  // int2 [NE]                10,000,000
// total ~275.6 MB

typedef unsigned short u16;
typedef unsigned int u32;

__device__ __forceinline__ u16 f2bf(float f) {
    u32 u = __float_as_uint(f);
    return (u16)((u + 0x7fffu + ((u >> 16) & 1u)) >> 16);   // RNE
}
__device__ __forceinline__ float bf2f(u16 b) {
    return __uint_as_float(((u32)b) << 16);
}
__device__ __forceinline__ u32 pack2(float lo, float hi) {
    return (u32)f2bf(lo) | ((u32)f2bf(hi) << 16);
}
__device__ __forceinline__ float sigmoidf_(float x) {
    return 1.f / (1.f + __expf(-x));
}

// ---------------- fnet: per-edge MLP 13->64->64->64, bf16 out ----------------
__global__ __launch_bounds__(256) void k_fnet(
    const float* __restrict__ ef,
    const float* __restrict__ W1, const float* __restrict__ b1,
    const float* __restrict__ W2, const float* __restrict__ b2,
    const float* __restrict__ W3, const float* __restrict__ b3,
    u16* __restrict__ wout)
{
    int e = blockIdx.x * 256 + threadIdx.x;
    if (e >= NE) return;
    float x[13];
#pragma unroll
    for (int k = 0; k < 13; ++k) x[k] = ef[(size_t)e * 13 + k];
    float h1[64];
#pragma unroll
    for (int j = 0; j < 64; ++j) {
        float a = b1[j];
#pragma unroll
        for (int k = 0; k < 13; ++k) a = fmaf(x[k], W1[j * 13 + k], a);
        h1[j] = fmaxf(a, 0.f);
    }
    float h2[64];
#pragma unroll
    for (int j = 0; j < 64; ++j) {
        float a = b2[j];
#pragma unroll
        for (int k = 0; k < 64; ++k) a = fmaf(h1[k], W2[j * 64 + k], a);
        h2[j] = fmaxf(a, 0.f);
    }
    uint4* out4 = (uint4*)(wout + (size_t)e * 64);
#pragma unroll
    for (int g = 0; g < 8; ++g) {
        float v[8];
#pragma unroll
        for (int jj = 0; jj < 8; ++jj) {
            int j = g * 8 + jj;
            float a = b3[j];
#pragma unroll
            for (int k = 0; k < 64; ++k) a = fmaf(h2[k], W3[j * 64 + k], a);
            v[jj] = a;
        }
        uint4 u;
        u.x = pack2(v[0], v[1]); u.y = pack2(v[2], v[3]);
        u.z = pack2(v[4], v[5]); u.w = pack2(v[6], v[7]);
        out4[g] = u;
    }
}

// ---------------- degree counting ----------------
__global__ void k_count(const int* __restrict__ idx, int* __restrict__ counts)
{
    int e = blockIdx.x * 256 + threadIdx.x;
    if (e < NE) atomicAdd(&counts[idx[e]], 1);
}

// ---------------- two-level exclusive scan over counts ----------------
__global__ void k_scan_partial(const int* __restrict__ counts, int* __restrict__ bsum)
{
    __shared__ int s[256];
    int i = blockIdx.x * 256 + threadIdx.x;
    int v = (i < NN) ? counts[i] : 0;
    s[threadIdx.x] = v; __syncthreads();
    for (int off = 128; off > 0; off >>= 1) {
        if (threadIdx.x < off) s[threadIdx.x] += s[threadIdx.x + off];
        __syncthreads();
    }
    if (threadIdx.x == 0) bsum[blockIdx.x] = s[0];
}

__global__ void k_scan_bsum(const int* __restrict__ bsum, int* __restrict__ bsumex)
{
    __shared__ int s[512];
    int t = threadIdx.x;
    int v0 = (t < 391) ? bsum[t] : 0;
    s[t] = v0; __syncthreads();
    for (int off = 1; off < 512; off <<= 1) {
        int add = (t >= off) ? s[t - off] : 0;
        __syncthreads();
        s[t] += add;
        __syncthreads();
    }
    if (t < 391) bsumex[t] = s[t] - v0;
}

__global__ void k_scan_final(const int* __restrict__ counts, const int* __restrict__ bsumex,
                             int* __restrict__ rowstart, int* __restrict__ cursor,
                             float* __restrict__ invdeg)
{
    __shared__ int s[256];
    int t = threadIdx.x;
    int i = blockIdx.x * 256 + t;
    int c = (i < NN) ? counts[i] : 0;
    s[t] = c; __syncthreads();
    for (int off = 1; off < 256; off <<= 1) {
        int add = (t >= off) ? s[t - off] : 0;
        __syncthreads();
        s[t] += add;
        __syncthreads();
    }
    int ex = s[t] - c + bsumex[blockIdx.x];
    if (i < NN) {
        rowstart[i] = ex;
        cursor[i] = ex;
        invdeg[i] = 1.f / (float)(c > 1 ? c : 1);
    }
    if (i == 0) rowstart[NN] = NE;
}

// ---------------- scatter edges into CSR order ----------------
__global__ void k_scatter(const int* __restrict__ idx, int* __restrict__ cursor,
                          int2* __restrict__ rec)
{
    int e = blockIdx.x * 256 + threadIdx.x;
    if (e < NE) {
        int d = idx[e];         // dst = edge_index[0]
        int s = idx[NE + e];    // src = edge_index[1]
        int p = atomicAdd(&cursor[d], 1);
        rec[p] = make_int2(s, e);
    }
}

// ---------------- copy hx0 into out column 0 ----------------
__global__ void k_init(const float4* __restrict__ hx4, float* __restrict__ outp)
{
    int i = blockIdx.x * 256 + threadIdx.x;      // < NN*16
    int n = i >> 4, q = i & 15;
    ((float4*)(outp + (size_t)n * 256))[q] = hx4[i];
}

// ---------------- aggregation: wave per node ----------------
__global__ __launch_bounds__(256) void k_agg(
    const float* __restrict__ outp, const u16* __restrict__ w,
    const int2* __restrict__ rec, const int* __restrict__ rowstart,
    const float* __restrict__ invdeg, float* __restrict__ agg, int it)
{
    int lane = threadIdx.x & 63;
    int n = blockIdx.x * 4 + (threadIdx.x >> 6);     // 25000*4 == NN exactly
    n = __builtin_amdgcn_readfirstlane(n);
    int p0 = rowstart[n], p1 = rowstart[n + 1];
    const float* hxcol = outp + (size_t)it * 64 + lane;
    float acc = 0.f;
    for (int p = p0; p < p1; ++p) {
        int2 r = rec[p];
        float hv = hxcol[(size_t)r.x * 256];
        float wv = bf2f(w[(size_t)r.y * 64 + lane]);
        acc = fmaf(hv, wv, acc);
    }
    agg[(size_t)n * 64 + lane] = acc * invdeg[n];
}

// ---------------- GRU part A: gate GEMM + gi/gh GEMMs + inorm stats ----------------
__global__ __launch_bounds__(256) void k_gru_a(
    const float* __restrict__ outp, const float* __restrict__ agg,
    u16* __restrict__ gi, u16* __restrict__ gh, float4* __restrict__ stats,
    const float* __restrict__ Wig, const float* __restrict__ big,
    const float* __restrict__ Wih, const float* __restrict__ Whh, int it)
{
    int n = blockIdx.x * 256 + threadIdx.x;
    if (n >= NN) return;
    float hx[64], inp[64];
    const float4* h4 = (const float4*)(outp + (size_t)n * 256 + (size_t)it * 64);
    const float4* a4 = (const float4*)(agg + (size_t)n * 64);
#pragma unroll
    for (int q = 0; q < 16; ++q) {
        float4 t = h4[q];
        hx[4 * q] = t.x; hx[4 * q + 1] = t.y; hx[4 * q + 2] = t.z; hx[4 * q + 3] = t.w;
    }
#pragma unroll
    for (int q = 0; q < 16; ++q) {
        float4 t = a4[q];
        inp[4 * q] = t.x; inp[4 * q + 1] = t.y; inp[4 * q + 2] = t.z; inp[4 * q + 3] = t.w;
    }
    // input gate: inp = sigmoid(hx @ Wig.T + big) * agg
#pragma unroll
    for (int j = 0; j < 64; ++j) {
        float a = big[j];
#pragma unroll
        for (int k = 0; k < 64; ++k) a = fmaf(hx[k], Wig[j * 64 + k], a);
        inp[j] *= sigmoidf_(a);
    }
    // gh = hx @ Whh.T   (store unnormalized, accumulate stats)
    float sh = 0.f, qh = 0.f;
#pragma unroll 2
    for (int j = 0; j < 192; ++j) {
        float a = 0.f;
#pragma unroll
        for (int k = 0; k < 64; ++k) a = fmaf(hx[k], Whh[j * 64 + k], a);
        sh += a; qh += a * a;
        gh[(size_t)j * NN + n] = f2bf(a);
    }
    // gi = inp @ Wih.T
    float si = 0.f, qi = 0.f;
#pragma unroll 2
    for (int j = 0; j < 192; ++j) {
        float a = 0.f;
#pragma unroll
        for (int k = 0; k < 64; ++k) a = fmaf(inp[k], Wih[j * 64 + k], a);
        si += a; qi += a * a;
        gi[(size_t)j * NN + n] = f2bf(a);
    }
    float mi = si * (1.f / 192.f), mh = sh * (1.f / 192.f);
    float vi = qi * (1.f / 192.f) - mi * mi;
    float vh = qh * (1.f / 192.f) - mh * mh;
    stats[n] = make_float4(mi, rsqrtf(vi + EPSI), mh, rsqrtf(vh + EPSI));
}

// ---------------- GRU part B: normalize + gates + hx update ----------------
__global__ __launch_bounds__(256) void k_gru_b(
    float* __restrict__ outp, const u16* __restrict__ gi, const u16* __restrict__ gh,
    const float4* __restrict__ stats, const float* __restrict__ bih,
    const float* __restrict__ bhh, int it)
{
    int n = blockIdx.x * 256 + threadIdx.x;
    if (n >= NN) return;
    float4 st = stats[n];
    const float4* h4 = (const float4*)(outp + (size_t)n * 256 + (size_t)it * 64);
    float4* o4 = (float4*)(outp + (size_t)n * 256 + (size_t)(it + 1) * 64);
#pragma unroll 4
    for (int q = 0; q < 16; ++q) {
        float4 hv = h4[q];
        float hvv[4] = {hv.x, hv.y, hv.z, hv.w};
        float res[4];
#pragma unroll
        for (int u = 0; u < 4; ++u) {
            int f = 4 * q + u;
            float ir = (bf2f(gi[(size_t)f * NN + n]) - st.x) * st.y;
            float ii = (bf2f(gi[(size_t)(64 + f) * NN + n]) - st.x) * st.y;
            float in_ = (bf2f(gi[(size_t)(128 + f) * NN + n]) - st.x) * st.y;
            float hr = (bf2f(gh[(size_t)f * NN + n]) - st.z) * st.w;
            float hi = (bf2f(gh[(size_t)(64 + f) * NN + n]) - st.z) * st.w;
            float hn = (bf2f(gh[(size_t)(128 + f) * NN + n]) - st.z) * st.w;
            float rg = sigmoidf_(ir + bih[f] + hr + bhh[f]);
            float zg = sigmoidf_(ii + bih[64 + f] + hi + bhh[64 + f]);
            float ng = tanhf(in_ + bih[128 + f] + rg * (hn + bhh[128 + f]));
            res[u] = ng + zg * (hvv[u] - ng);
        }
        float4 r4; r4.x = res[0]; r4.y = res[1]; r4.z = res[2]; r4.w = res[3];
        o4[q] = r4;
    }
}

extern "C" void kernel_launch(void* const* d_in, const int* in_sizes, int n_in,
                              void* d_out, int out_size, void* d_ws, size_t ws_size,
                              hipStream_t stream)
{
    const float* hx  = (const float*)d_in[0];
    const int*   eix = (const int*)d_in[1];
    const float* ef  = (const float*)d_in[2];
    const float* fW1 = (const float*)d_in[3];
    const float* fb1 = (const float*)d_in[4];
    const float* fW2 = (const float*)d_in[5];
    const float* fb2 = (const float*)d_in[6];
    const float* fW3 = (const float*)d_in[7];
    const float* fb3 = (const float*)d_in[8];
    const float* Wih = (const float*)d_in[9];
    const float* Whh = (const float*)d_in[10];
    const float* bih = (const float*)d_in[11];
    const float* bhh = (const float*)d_in[12];
    const float* Wig = (const float*)d_in[13];
    const float* big = (const float*)d_in[14];
    float* outp = (float*)d_out;
    char* ws = (char*)d_ws;

    u16*    w      = (u16*)(ws + WS_W);
    float*  agg    = (float*)(ws + WS_AGG);
    u16*    gi     = (u16*)(ws + WS_GI);
    u16*    gh     = (u16*)(ws + WS_GH);
    float4* stats  = (float4*)(ws + WS_STATS);
    float*  invdeg = (float*)(ws + WS_INVDEG);
    int*    counts = (int*)(ws + WS_COUNTS);
    int*    rowst  = (int*)(ws + WS_ROWSTART);
    int*    cursor = (int*)(ws + WS_CURSOR);
    int*    bsum   = (int*)(ws + WS_BSUM);
    int*    bsumex = (int*)(ws + WS_BSUMEX);
    int2*   rec    = (int2*)(ws + WS_REC);

    hipMemsetAsync(counts, 0, NN * sizeof(int), stream);
    k_fnet<<<(NE + 255) / 256, 256, 0, stream>>>(ef, fW1, fb1, fW2, fb2, fW3, fb3, w);
    k_count<<<(NE + 255) / 256, 256, 0, stream>>>(eix, counts);
    k_scan_partial<<<391, 256, 0, stream>>>(counts, bsum);
    k_scan_bsum<<<1, 512, 0, stream>>>(bsum, bsumex);
    k_scan_final<<<391, 256, 0, stream>>>(counts, bsumex, rowst, cursor, invdeg);
    k_scatter<<<(NE + 255) / 256, 256, 0, stream>>>(eix, cursor, rec);
    k_init<<<6250, 256, 0, stream>>>((const float4*)hx, outp);

    for (int it = 0; it < 3; ++it) {
        k_agg<<<25000, 256, 0, stream>>>(outp, w, rec, rowst, invdeg, agg, it);
        k_gru_a<<<391, 256, 0, stream>>>(outp, agg, gi, gh, stats, Wig, big, Wih, Whh, it);
        k_gru_b<<<391, 256, 0, stream>>>(outp, gi, gh, stats, bih, bhh, it);
    }
}

// Round 2
// 2102.168 us; speedup vs baseline: 1.3873x; 1.3873x over previous
//
#include <hip/hip_runtime.h>
#include <math.h>

#define NN 100000
#define NE 1250000
#define EPSI 1e-5f

// ---- workspace layout (bytes) ----
#define WS_W        0ull          // bf16 [NE*64]            160,000,000
#define WS_AGG      160000000ull  // f32  [NN*64]             25,600,000
#define WS_GI       185600000ull  // bf16 [192*NN]            38,400,000
#define WS_GH       224000000ull  // bf16 [192*NN]            38,400,000
#define WS_STATS    262400000ull  // f32x4 [NN]                1,600,000
#define WS_INVDEG   264000000ull  // f32 [NN]                    400,000
#define WS_COUNTS   264400000ull  // i32 [NN]                    400,000
#define WS_ROWSTART 264800000ull  // i32 [NN+1]
#define WS_CURSOR   265200128ull  // i32 [NN]
#define WS_BSUM     265600128ull  // i32 [391]
#define WS_BSUMEX   265601792ull  // i32 [391]
#define WS_REC      265603584ull  // int2 [NE]                10,000,000
// total ~275.6 MB

typedef unsigned short u16;
typedef unsigned int u32;
typedef short s16x4 __attribute__((ext_vector_type(4)));
typedef short s16x8 __attribute__((ext_vector_type(8)));
typedef float f32x4 __attribute__((ext_vector_type(4)));
typedef u32 u32x4 __attribute__((ext_vector_type(4)));

__device__ __forceinline__ u16 f2bf(float f) {
    u32 u = __float_as_uint(f);
    return (u16)((u + 0x7fffu + ((u >> 16) & 1u)) >> 16);   // RNE
}
__device__ __forceinline__ float bf2f(u16 b) {
    return __uint_as_float(((u32)b) << 16);
}
__device__ __forceinline__ u32 pack2(float lo, float hi) {
    return (u32)f2bf(lo) | ((u32)f2bf(hi) << 16);
}
__device__ __forceinline__ float sigmoidf_(float x) {
    return 1.f / (1.f + __expf(-x));
}
__device__ __forceinline__ s16x8 lds_frag(const u16* p) {
    // p is 8-byte aligned by construction (row stride 68 bf16 = 136 B, offsets ×16B)
    s16x4 lo = *(const s16x4*)p;
    s16x4 hi = *(const s16x4*)(p + 4);
    return __builtin_shufflevector(lo, hi, 0, 1, 2, 3, 4, 5, 6, 7);
}

// ============ fnet via MFMA: per-edge MLP 13->64->64->64, bf16 out ============
// Block = 256 threads = 4 waves; wave owns 32 edges (2 M-subtiles of 16).
// mfma_f32_16x16x32_bf16; A[m=lane&15][k=(lane>>4)*8+j]; B[k][n=lane&15] same k map;
// C/D: col=lane&15, row=(lane>>4)*4+reg  (verified layouts per guide §3).
__global__ __launch_bounds__(256) void k_fnet_mfma(
    const float* __restrict__ ef,
    const float* __restrict__ W1, const float* __restrict__ b1,
    const float* __restrict__ W2, const float* __restrict__ b2,
    const float* __restrict__ W3, const float* __restrict__ b3,
    u16* __restrict__ wout)
{
    __shared__ u16 w1l[64 * 16];        // [n][k] k padded 13->16
    __shared__ u16 w2l[64 * 68];        // [n][k] stride 68 (pad breaks bank aliasing)
    __shared__ u16 w3l[64 * 68];
    __shared__ u16 hbuf[4][32 * 68];    // per-wave transpose buffer [m][feat], stride 68

    int tid = threadIdx.x;
    // ---- stage weights to LDS (bf16) ----
    for (int i = tid; i < 64 * 16; i += 256) w1l[i] = 0;
    for (int i = tid; i < 4096; i += 256) w2l[(i >> 6) * 68 + (i & 63)] = f2bf(W2[i]);
    for (int i = tid; i < 4096; i += 256) w3l[(i >> 6) * 68 + (i & 63)] = f2bf(W3[i]);
    __syncthreads();
    for (int i = tid; i < 832; i += 256) {
        int n = i / 13, k = i - n * 13;
        w1l[n * 16 + k] = f2bf(W1[i]);
    }
    __syncthreads();

    int wave = tid >> 6, lane = tid & 63;
    int q = lane >> 4, t = lane & 15;
    int ebase = blockIdx.x * 128 + wave * 32;
    u16* hb = hbuf[wave];

    // per-lane biases (col = ni*16+t)
    float b1v[4], b2v[4], b3v[4];
#pragma unroll
    for (int ni = 0; ni < 4; ++ni) {
        b1v[ni] = b1[ni * 16 + t];
        b2v[ni] = b2[ni * 16 + t];
        b3v[ni] = b3[ni * 16 + t];
    }

    const s16x8 zfrag = {0, 0, 0, 0, 0, 0, 0, 0};

    // ---------- layer 1: [32,13(pad32)] @ W1^T -> [32,64], relu ----------
    s16x8 a1[2];
#pragma unroll
    for (int mi = 0; mi < 2; ++mi) {
        int e = ebase + mi * 16 + t;
        s16x8 a = zfrag;
        if (e < NE) {
#pragma unroll
            for (int j = 0; j < 8; ++j) {
                int k = q * 8 + j;
                float v = (k < 13) ? ef[(size_t)e * 13 + k] : 0.f;
                a[j] = (short)f2bf(v);
            }
        }
        a1[mi] = a;
    }
    s16x8 B1f[4];
#pragma unroll
    for (int ni = 0; ni < 4; ++ni) {
        s16x8 b = zfrag;
        if (q < 2) b = lds_frag(&w1l[(ni * 16 + t) * 16 + q * 8]);
        B1f[ni] = b;
    }
#pragma unroll
    for (int ni = 0; ni < 4; ++ni) {
#pragma unroll
        for (int mi = 0; mi < 2; ++mi) {
            f32x4 acc = {b1v[ni], b1v[ni], b1v[ni], b1v[ni]};
            acc = __builtin_amdgcn_mfma_f32_16x16x32_bf16(a1[mi], B1f[ni], acc, 0, 0, 0);
#pragma unroll
            for (int r = 0; r < 4; ++r)
                hb[(mi * 16 + q * 4 + r) * 68 + ni * 16 + t] = f2bf(fmaxf(acc[r], 0.f));
        }
    }

    // ---------- layer 2: [32,64] @ W2^T -> [32,64], relu ----------
    s16x8 a2[2][2];
#pragma unroll
    for (int mi = 0; mi < 2; ++mi)
#pragma unroll
        for (int ks = 0; ks < 2; ++ks)
            a2[mi][ks] = lds_frag(&hb[(mi * 16 + t) * 68 + ks * 32 + q * 8]);
#pragma unroll
    for (int ni = 0; ni < 4; ++ni) {
        s16x8 b0 = lds_frag(&w2l[(ni * 16 + t) * 68 + q * 8]);
        s16x8 b1f = lds_frag(&w2l[(ni * 16 + t) * 68 + 32 + q * 8]);
#pragma unroll
        for (int mi = 0; mi < 2; ++mi) {
            f32x4 acc = {b2v[ni], b2v[ni], b2v[ni], b2v[ni]};
            acc = __builtin_amdgcn_mfma_f32_16x16x32_bf16(a2[mi][0], b0, acc, 0, 0, 0);
            acc = __builtin_amdgcn_mfma_f32_16x16x32_bf16(a2[mi][1], b1f, acc, 0, 0, 0);
#pragma unroll
            for (int r = 0; r < 4; ++r)
                hb[(mi * 16 + q * 4 + r) * 68 + ni * 16 + t] = f2bf(fmaxf(acc[r], 0.f));
        }
    }

    // ---------- layer 3: [32,64] @ W3^T -> [32,64], +bias, no relu ----------
    s16x8 a3[2][2];
#pragma unroll
    for (int mi = 0; mi < 2; ++mi)
#pragma unroll
        for (int ks = 0; ks < 2; ++ks)
            a3[mi][ks] = lds_frag(&hb[(mi * 16 + t) * 68 + ks * 32 + q * 8]);
#pragma unroll
    for (int ni = 0; ni < 4; ++ni) {
        s16x8 b0 = lds_frag(&w3l[(ni * 16 + t) * 68 + q * 8]);
        s16x8 b1f = lds_frag(&w3l[(ni * 16 + t) * 68 + 32 + q * 8]);
#pragma unroll
        for (int mi = 0; mi < 2; ++mi) {
            f32x4 acc = {b3v[ni], b3v[ni], b3v[ni], b3v[ni]};
            acc = __builtin_amdgcn_mfma_f32_16x16x32_bf16(a3[mi][0], b0, acc, 0, 0, 0);
            acc = __builtin_amdgcn_mfma_f32_16x16x32_bf16(a3[mi][1], b1f, acc, 0, 0, 0);
#pragma unroll
            for (int r = 0; r < 4; ++r)
                hb[(mi * 16 + q * 4 + r) * 68 + ni * 16 + t] = f2bf(acc[r]);
        }
    }

    // ---------- coalesced store: wave's 32 edges x 64 bf16 via LDS readback ----------
#pragma unroll
    for (int p = 0; p < 4; ++p) {
        int g = p * 64 + lane;
        int m = g >> 3, qq = g & 7;
        int e = ebase + m;
        if (e < NE) {
            const u16* sp = &hb[m * 68 + qq * 8];
            s16x4 lo = *(const s16x4*)sp;
            s16x4 hi = *(const s16x4*)(sp + 4);
            struct H128 { s16x4 a, b; } h;
            h.a = lo; h.b = hi;
            u32x4 v = __builtin_bit_cast(u32x4, h);
            *(u32x4*)(wout + (size_t)e * 64 + qq * 8) = v;
        }
    }
}

// ---------------- degree counting ----------------
__global__ void k_count(const int* __restrict__ idx, int* __restrict__ counts)
{
    int e = blockIdx.x * 256 + threadIdx.x;
    if (e < NE) atomicAdd(&counts[idx[e]], 1);
}

// ---------------- two-level exclusive scan over counts ----------------
__global__ void k_scan_partial(const int* __restrict__ counts, int* __restrict__ bsum)
{
    __shared__ int s[256];
    int i = blockIdx.x * 256 + threadIdx.x;
    int v = (i < NN) ? counts[i] : 0;
    s[threadIdx.x] = v; __syncthreads();
    for (int off = 128; off > 0; off >>= 1) {
        if (threadIdx.x < off) s[threadIdx.x] += s[threadIdx.x + off];
        __syncthreads();
    }
    if (threadIdx.x == 0) bsum[blockIdx.x] = s[0];
}

__global__ void k_scan_bsum(const int* __restrict__ bsum, int* __restrict__ bsumex)
{
    __shared__ int s[512];
    int t = threadIdx.x;
    int v0 = (t < 391) ? bsum[t] : 0;
    s[t] = v0; __syncthreads();
    for (int off = 1; off < 512; off <<= 1) {
        int add = (t >= off) ? s[t - off] : 0;
        __syncthreads();
        s[t] += add;
        __syncthreads();
    }
    if (t < 391) bsumex[t] = s[t] - v0;
}

__global__ void k_scan_final(const int* __restrict__ counts, const int* __restrict__ bsumex,
                             int* __restrict__ rowstart, int* __restrict__ cursor,
                             float* __restrict__ invdeg)
{
    __shared__ int s[256];
    int t = threadIdx.x;
    int i = blockIdx.x * 256 + t;
    int c = (i < NN) ? counts[i] : 0;
    s[t] = c; __syncthreads();
    for (int off = 1; off < 256; off <<= 1) {
        int add = (t >= off) ? s[t - off] : 0;
        __syncthreads();
        s[t] += add;
        __syncthreads();
    }
    int ex = s[t] - c + bsumex[blockIdx.x];
    if (i < NN) {
        rowstart[i] = ex;
        cursor[i] = ex;
        invdeg[i] = 1.f / (float)(c > 1 ? c : 1);
    }
    if (i == 0) rowstart[NN] = NE;
}

// ---------------- scatter edges into CSR order ----------------
__global__ void k_scatter(const int* __restrict__ idx, int* __restrict__ cursor,
                          int2* __restrict__ rec)
{
    int e = blockIdx.x * 256 + threadIdx.x;
    if (e < NE) {
        int d = idx[e];         // dst = edge_index[0]
        int s = idx[NE + e];    // src = edge_index[1]
        int p = atomicAdd(&cursor[d], 1);
        rec[p] = make_int2(s, e);
    }
}

// ---------------- copy hx0 into out column 0 ----------------
__global__ void k_init(const float4* __restrict__ hx4, float* __restrict__ outp)
{
    int i = blockIdx.x * 256 + threadIdx.x;      // < NN*16
    int n = i >> 4, q = i & 15;
    ((float4*)(outp + (size_t)n * 256))[q] = hx4[i];
}

// ---------------- aggregation: wave per node ----------------
__global__ __launch_bounds__(256) void k_agg(
    const float* __restrict__ outp, const u16* __restrict__ w,
    const int2* __restrict__ rec, const int* __restrict__ rowstart,
    const float* __restrict__ invdeg, float* __restrict__ agg, int it)
{
    int lane = threadIdx.x & 63;
    int n = blockIdx.x * 4 + (threadIdx.x >> 6);     // 25000*4 == NN exactly
    n = __builtin_amdgcn_readfirstlane(n);
    int p0 = rowstart[n], p1 = rowstart[n + 1];
    const float* hxcol = outp + (size_t)it * 64 + lane;
    float acc = 0.f;
    for (int p = p0; p < p1; ++p) {
        int2 r = rec[p];
        float hv = hxcol[(size_t)r.x * 256];
        float wv = bf2f(w[(size_t)r.y * 64 + lane]);
        acc = fmaf(hv, wv, acc);
    }
    agg[(size_t)n * 64 + lane] = acc * invdeg[n];
}

// ---------------- GRU part A: gate GEMM + gi/gh GEMMs + inorm stats ----------------
__global__ __launch_bounds__(256) void k_gru_a(
    const float* __restrict__ outp, const float* __restrict__ agg,
    u16* __restrict__ gi, u16* __restrict__ gh, float4* __restrict__ stats,
    const float* __restrict__ Wig, const float* __restrict__ big,
    const float* __restrict__ Wih, const float* __restrict__ Whh, int it)
{
    int n = blockIdx.x * 256 + threadIdx.x;
    if (n >= NN) return;
    float hx[64], inp[64];
    const float4* h4 = (const float4*)(outp + (size_t)n * 256 + (size_t)it * 64);
    const float4* a4 = (const float4*)(agg + (size_t)n * 64);
#pragma unroll
    for (int q = 0; q < 16; ++q) {
        float4 t = h4[q];
        hx[4 * q] = t.x; hx[4 * q + 1] = t.y; hx[4 * q + 2] = t.z; hx[4 * q + 3] = t.w;
    }
#pragma unroll
    for (int q = 0; q < 16; ++q) {
        float4 t = a4[q];
        inp[4 * q] = t.x; inp[4 * q + 1] = t.y; inp[4 * q + 2] = t.z; inp[4 * q + 3] = t.w;
    }
    // input gate: inp = sigmoid(hx @ Wig.T + big) * agg
#pragma unroll
    for (int j = 0; j < 64; ++j) {
        float a = big[j];
#pragma unroll
        for (int k = 0; k < 64; ++k) a = fmaf(hx[k], Wig[j * 64 + k], a);
        inp[j] *= sigmoidf_(a);
    }
    // gh = hx @ Whh.T   (store unnormalized, accumulate stats)
    float sh = 0.f, qh = 0.f;
#pragma unroll 2
    for (int j = 0; j < 192; ++j) {
        float a = 0.f;
#pragma unroll
        for (int k = 0; k < 64; ++k) a = fmaf(hx[k], Whh[j * 64 + k], a);
        sh += a; qh += a * a;
        gh[(size_t)j * NN + n] = f2bf(a);
    }
    // gi = inp @ Wih.T
    float si = 0.f, qi = 0.f;
#pragma unroll 2
    for (int j = 0; j < 192; ++j) {
        float a = 0.f;
#pragma unroll
        for (int k = 0; k < 64; ++k) a = fmaf(inp[k], Wih[j * 64 + k], a);
        si += a; qi += a * a;
        gi[(size_t)j * NN + n] = f2bf(a);
    }
    float mi = si * (1.f / 192.f), mh = sh * (1.f / 192.f);
    float vi = qi * (1.f / 192.f) - mi * mi;
    float vh = qh * (1.f / 192.f) - mh * mh;
    stats[n] = make_float4(mi, rsqrtf(vi + EPSI), mh, rsqrtf(vh + EPSI));
}

// ---------------- GRU part B: normalize + gates + hx update ----------------
__global__ __launch_bounds__(256) void k_gru_b(
    float* __restrict__ outp, const u16* __restrict__ gi, const u16* __restrict__ gh,
    const float4* __restrict__ stats, const float* __restrict__ bih,
    const float* __restrict__ bhh, int it)
{
    int n = blockIdx.x * 256 + threadIdx.x;
    if (n >= NN) return;
    float4 st = stats[n];
    const float4* h4 = (const float4*)(outp + (size_t)n * 256 + (size_t)it * 64);
    float4* o4 = (float4*)(outp + (size_t)n * 256 + (size_t)(it + 1) * 64);
#pragma unroll 4
    for (int q = 0; q < 16; ++q) {
        float4 hv = h4[q];
        float hvv[4] = {hv.x, hv.y, hv.z, hv.w};
        float res[4];
#pragma unroll
        for (int u = 0; u < 4; ++u) {
            int f = 4 * q + u;
            float ir = (bf2f(gi[(size_t)f * NN + n]) - st.x) * st.y;
            float ii = (bf2f(gi[(size_t)(64 + f) * NN + n]) - st.x) * st.y;
            float in_ = (bf2f(gi[(size_t)(128 + f) * NN + n]) - st.x) * st.y;
            float hr = (bf2f(gh[(size_t)f * NN + n]) - st.z) * st.w;
            float hi = (bf2f(gh[(size_t)(64 + f) * NN + n]) - st.z) * st.w;
            float hn = (bf2f(gh[(size_t)(128 + f) * NN + n]) - st.z) * st.w;
            float rg = sigmoidf_(ir + bih[f] + hr + bhh[f]);
            float zg = sigmoidf_(ii + bih[64 + f] + hi + bhh[64 + f]);
            float ng = tanhf(in_ + bih[128 + f] + rg * (hn + bhh[128 + f]));
            res[u] = ng + zg * (hvv[u] - ng);
        }
        float4 r4; r4.x = res[0]; r4.y = res[1]; r4.z = res[2]; r4.w = res[3];
        o4[q] = r4;
    }
}

extern "C" void kernel_launch(void* const* d_in, const int* in_sizes, int n_in,
                              void* d_out, int out_size, void* d_ws, size_t ws_size,
                              hipStream_t stream)
{
    const float* hx  = (const float*)d_in[0];
    const int*   eix = (const int*)d_in[1];
    const float* ef  = (const float*)d_in[2];
    const float* fW1 = (const float*)d_in[3];
    const float* fb1 = (const float*)d_in[4];
    const float* fW2 = (const float*)d_in[5];
    const float* fb2 = (const float*)d_in[6];
    const float* fW3 = (const float*)d_in[7];
    const float* fb3 = (const float*)d_in[8];
    const float* Wih = (const float*)d_in[9];
    const float* Whh = (const float*)d_in[10];
    const float* bih = (const float*)d_in[11];
    const float* bhh = (const float*)d_in[12];
    const float* Wig = (const float*)d_in[13];
    const float* big = (const float*)d_in[14];
    float* outp = (float*)d_out;
    char* ws = (char*)d_ws;

    u16*    w      = (u16*)(ws + WS_W);
    float*  agg    = (float*)(ws + WS_AGG);
    u16*    gi     = (u16*)(ws + WS_GI);
    u16*    gh     = (u16*)(ws + WS_GH);
    float4* stats  = (float4*)(ws + WS_STATS);
    float*  invdeg = (float*)(ws + WS_INVDEG);
    int*    counts = (int*)(ws + WS_COUNTS);
    int*    rowst  = (int*)(ws + WS_ROWSTART);
    int*    cursor = (int*)(ws + WS_CURSOR);
    int*    bsum   = (int*)(ws + WS_BSUM);
    int*    bsumex = (int*)(ws + WS_BSUMEX);
    int2*   rec    = (int2*)(ws + WS_REC);

    hipMemsetAsync(counts, 0, NN * sizeof(int), stream);
    k_fnet_mfma<<<9766, 256, 0, stream>>>(ef, fW1, fb1, fW2, fb2, fW3, fb3, w);
    k_count<<<(NE + 255) / 256, 256, 0, stream>>>(eix, counts);
    k_scan_partial<<<391, 256, 0, stream>>>(counts, bsum);
    k_scan_bsum<<<1, 512, 0, stream>>>(bsum, bsumex);
    k_scan_final<<<391, 256, 0, stream>>>(counts, bsumex, rowst, cursor, invdeg);
    k_scatter<<<(NE + 255) / 256, 256, 0, stream>>>(eix, cursor, rec);
    k_init<<<6250, 256, 0, stream>>>((const float4*)hx, outp);

    for (int it = 0; it < 3; ++it) {
        k_agg<<<25000, 256, 0, stream>>>(outp, w, rec, rowst, invdeg, agg, it);
        k_gru_a<<<391, 256, 0, stream>>>(outp, agg, gi, gh, stats, Wig, big, Wih, Whh, it);
        k_gru_b<<<391, 256, 0, stream>>>(outp, gi, gh, stats, bih, bhh, it);
    }
}

// Round 3
// 976.280 us; speedup vs baseline: 2.9872x; 2.1532x over previous
//
#include <hip/hip_runtime.h>
#include <math.h>

#define NN 100000
#define NE 1250000
#define EPSI 1e-5f

// ---- workspace layout (bytes) ----
#define WS_W        0ull          // bf16 [NE*64]            160,000,000
#define WS_AGG      160000000ull  // f32  [NN*64]             25,600,000
#define WS_WB       185600000ull  // bf16 weights: Wig[4096] Whh[12288] Wih[12288]
#define WS_INVDEG   264000000ull  // f32 [NN]
#define WS_COUNTS   264400000ull  // i32 [NN]
#define WS_ROWSTART 264800000ull  // i32 [NN+1]
#define WS_CURSOR   265200128ull  // i32 [NN]
#define WS_BSUM     265600128ull  // i32 [391]
#define WS_BSUMEX   265601792ull  // i32 [391]
#define WS_REC      265603584ull  // int2 [NE]                10,000,000

typedef unsigned short u16;
typedef unsigned int u32;
typedef short s16x4 __attribute__((ext_vector_type(4)));
typedef short s16x8 __attribute__((ext_vector_type(8)));
typedef float f32x4 __attribute__((ext_vector_type(4)));
typedef u32 u32x4 __attribute__((ext_vector_type(4)));

__device__ __forceinline__ u16 f2bf(float f) {
    u32 u = __float_as_uint(f);
    return (u16)((u + 0x7fffu + ((u >> 16) & 1u)) >> 16);   // RNE
}
__device__ __forceinline__ float bf2f(u16 b) {
    return __uint_as_float(((u32)b) << 16);
}
__device__ __forceinline__ u32 pack2(float lo, float hi) {
    return (u32)f2bf(lo) | ((u32)f2bf(hi) << 16);
}
__device__ __forceinline__ float sigmoidf_(float x) {
    return 1.f / (1.f + __expf(-x));
}
__device__ __forceinline__ s16x8 lds_frag(const u16* p) {
    s16x4 lo = *(const s16x4*)p;
    s16x4 hi = *(const s16x4*)(p + 4);
    return __builtin_shufflevector(lo, hi, 0, 1, 2, 3, 4, 5, 6, 7);
}
__device__ __forceinline__ s16x8 gfrag(const u16* W, int n, int ks, int q) {
    // W row-major [64 cols], 16-byte aligned chunks
    return *(const s16x8*)(W + n * 64 + ks * 32 + q * 8);
}
__device__ __forceinline__ float unpk(const u32* p, int r) {
    u32 v = p[r >> 1];
    return bf2f((u16)((r & 1) ? (v >> 16) : (v & 0xffffu)));
}

// ============ fnet via MFMA: per-edge MLP 13->64->64->64, bf16 out ============
__global__ __launch_bounds__(256) void k_fnet_mfma(
    const float* __restrict__ ef,
    const float* __restrict__ W1, const float* __restrict__ b1,
    const float* __restrict__ W2, const float* __restrict__ b2,
    const float* __restrict__ W3, const float* __restrict__ b3,
    u16* __restrict__ wout)
{
    __shared__ u16 w1l[64 * 16];
    __shared__ u16 w2l[64 * 68];
    __shared__ u16 w3l[64 * 68];
    __shared__ u16 hbuf[4][32 * 68];

    int tid = threadIdx.x;
    for (int i = tid; i < 64 * 16; i += 256) w1l[i] = 0;
    for (int i = tid; i < 4096; i += 256) w2l[(i >> 6) * 68 + (i & 63)] = f2bf(W2[i]);
    for (int i = tid; i < 4096; i += 256) w3l[(i >> 6) * 68 + (i & 63)] = f2bf(W3[i]);
    __syncthreads();
    for (int i = tid; i < 832; i += 256) {
        int n = i / 13, k = i - n * 13;
        w1l[n * 16 + k] = f2bf(W1[i]);
    }
    __syncthreads();

    int wave = tid >> 6, lane = tid & 63;
    int q = lane >> 4, t = lane & 15;
    int ebase = blockIdx.x * 128 + wave * 32;
    u16* hb = hbuf[wave];

    float b1v[4], b2v[4], b3v[4];
#pragma unroll
    for (int ni = 0; ni < 4; ++ni) {
        b1v[ni] = b1[ni * 16 + t];
        b2v[ni] = b2[ni * 16 + t];
        b3v[ni] = b3[ni * 16 + t];
    }

    const s16x8 zfrag = {0, 0, 0, 0, 0, 0, 0, 0};

    // layer 1
    s16x8 a1[2];
#pragma unroll
    for (int mi = 0; mi < 2; ++mi) {
        int e = ebase + mi * 16 + t;
        s16x8 a = zfrag;
        if (e < NE) {
#pragma unroll
            for (int j = 0; j < 8; ++j) {
                int k = q * 8 + j;
                float v = (k < 13) ? ef[(size_t)e * 13 + k] : 0.f;
                a[j] = (short)f2bf(v);
            }
        }
        a1[mi] = a;
    }
    s16x8 B1f[4];
#pragma unroll
    for (int ni = 0; ni < 4; ++ni) {
        s16x8 b = zfrag;
        if (q < 2) b = lds_frag(&w1l[(ni * 16 + t) * 16 + q * 8]);
        B1f[ni] = b;
    }
#pragma unroll
    for (int ni = 0; ni < 4; ++ni) {
#pragma unroll
        for (int mi = 0; mi < 2; ++mi) {
            f32x4 acc = {b1v[ni], b1v[ni], b1v[ni], b1v[ni]};
            acc = __builtin_amdgcn_mfma_f32_16x16x32_bf16(a1[mi], B1f[ni], acc, 0, 0, 0);
#pragma unroll
            for (int r = 0; r < 4; ++r)
                hb[(mi * 16 + q * 4 + r) * 68 + ni * 16 + t] = f2bf(fmaxf(acc[r], 0.f));
        }
    }

    // layer 2
    s16x8 a2[2][2];
#pragma unroll
    for (int mi = 0; mi < 2; ++mi)
#pragma unroll
        for (int ks = 0; ks < 2; ++ks)
            a2[mi][ks] = lds_frag(&hb[(mi * 16 + t) * 68 + ks * 32 + q * 8]);
#pragma unroll
    for (int ni = 0; ni < 4; ++ni) {
        s16x8 b0 = lds_frag(&w2l[(ni * 16 + t) * 68 + q * 8]);
        s16x8 b1f = lds_frag(&w2l[(ni * 16 + t) * 68 + 32 + q * 8]);
#pragma unroll
        for (int mi = 0; mi < 2; ++mi) {
            f32x4 acc = {b2v[ni], b2v[ni], b2v[ni], b2v[ni]};
            acc = __builtin_amdgcn_mfma_f32_16x16x32_bf16(a2[mi][0], b0, acc, 0, 0, 0);
            acc = __builtin_amdgcn_mfma_f32_16x16x32_bf16(a2[mi][1], b1f, acc, 0, 0, 0);
#pragma unroll
            for (int r = 0; r < 4; ++r)
                hb[(mi * 16 + q * 4 + r) * 68 + ni * 16 + t] = f2bf(fmaxf(acc[r], 0.f));
        }
    }

    // layer 3
    s16x8 a3[2][2];
#pragma unroll
    for (int mi = 0; mi < 2; ++mi)
#pragma unroll
        for (int ks = 0; ks < 2; ++ks)
            a3[mi][ks] = lds_frag(&hb[(mi * 16 + t) * 68 + ks * 32 + q * 8]);
#pragma unroll
    for (int ni = 0; ni < 4; ++ni) {
        s16x8 b0 = lds_frag(&w3l[(ni * 16 + t) * 68 + q * 8]);
        s16x8 b1f = lds_frag(&w3l[(ni * 16 + t) * 68 + 32 + q * 8]);
#pragma unroll
        for (int mi = 0; mi < 2; ++mi) {
            f32x4 acc = {b3v[ni], b3v[ni], b3v[ni], b3v[ni]};
            acc = __builtin_amdgcn_mfma_f32_16x16x32_bf16(a3[mi][0], b0, acc, 0, 0, 0);
            acc = __builtin_amdgcn_mfma_f32_16x16x32_bf16(a3[mi][1], b1f, acc, 0, 0, 0);
#pragma unroll
            for (int r = 0; r < 4; ++r)
                hb[(mi * 16 + q * 4 + r) * 68 + ni * 16 + t] = f2bf(acc[r]);
        }
    }

    // coalesced store
#pragma unroll
    for (int p = 0; p < 4; ++p) {
        int g = p * 64 + lane;
        int m = g >> 3, qq = g & 7;
        int e = ebase + m;
        if (e < NE) {
            const u16* sp = &hb[m * 68 + qq * 8];
            s16x4 lo = *(const s16x4*)sp;
            s16x4 hi = *(const s16x4*)(sp + 4);
            struct H128 { s16x4 a, b; } h;
            h.a = lo; h.b = hi;
            u32x4 v = __builtin_bit_cast(u32x4, h);
            *(u32x4*)(wout + (size_t)e * 64 + qq * 8) = v;
        }
    }
}

// ---------------- prep: convert GRU weights to bf16 row-major ----------------
__global__ void k_prep_w(const float* __restrict__ Wig, const float* __restrict__ Whh,
                         const float* __restrict__ Wih, u16* __restrict__ wb)
{
    int i = blockIdx.x * 256 + threadIdx.x;   // < 28672
    if (i < 4096) wb[i] = f2bf(Wig[i]);
    else if (i < 16384) wb[i] = f2bf(Whh[i - 4096]);
    else if (i < 28672) wb[i] = f2bf(Wih[i - 16384]);
}

// ---------------- degree counting ----------------
__global__ void k_count(const int* __restrict__ idx, int* __restrict__ counts)
{
    int e = blockIdx.x * 256 + threadIdx.x;
    if (e < NE) atomicAdd(&counts[idx[e]], 1);
}

// ---------------- two-level exclusive scan over counts ----------------
__global__ void k_scan_partial(const int* __restrict__ counts, int* __restrict__ bsum)
{
    __shared__ int s[256];
    int i = blockIdx.x * 256 + threadIdx.x;
    int v = (i < NN) ? counts[i] : 0;
    s[threadIdx.x] = v; __syncthreads();
    for (int off = 128; off > 0; off >>= 1) {
        if (threadIdx.x < off) s[threadIdx.x] += s[threadIdx.x + off];
        __syncthreads();
    }
    if (threadIdx.x == 0) bsum[blockIdx.x] = s[0];
}

__global__ void k_scan_bsum(const int* __restrict__ bsum, int* __restrict__ bsumex)
{
    __shared__ int s[512];
    int t = threadIdx.x;
    int v0 = (t < 391) ? bsum[t] : 0;
    s[t] = v0; __syncthreads();
    for (int off = 1; off < 512; off <<= 1) {
        int add = (t >= off) ? s[t - off] : 0;
        __syncthreads();
        s[t] += add;
        __syncthreads();
    }
    if (t < 391) bsumex[t] = s[t] - v0;
}

__global__ void k_scan_final(const int* __restrict__ counts, const int* __restrict__ bsumex,
                             int* __restrict__ rowstart, int* __restrict__ cursor,
                             float* __restrict__ invdeg)
{
    __shared__ int s[256];
    int t = threadIdx.x;
    int i = blockIdx.x * 256 + t;
    int c = (i < NN) ? counts[i] : 0;
    s[t] = c; __syncthreads();
    for (int off = 1; off < 256; off <<= 1) {
        int add = (t >= off) ? s[t - off] : 0;
        __syncthreads();
        s[t] += add;
        __syncthreads();
    }
    int ex = s[t] - c + bsumex[blockIdx.x];
    if (i < NN) {
        rowstart[i] = ex;
        cursor[i] = ex;
        invdeg[i] = 1.f / (float)(c > 1 ? c : 1);
    }
    if (i == 0) rowstart[NN] = NE;
}

// ---------------- scatter edges into CSR order ----------------
__global__ void k_scatter(const int* __restrict__ idx, int* __restrict__ cursor,
                          int2* __restrict__ rec)
{
    int e = blockIdx.x * 256 + threadIdx.x;
    if (e < NE) {
        int d = idx[e];
        int s = idx[NE + e];
        int p = atomicAdd(&cursor[d], 1);
        rec[p] = make_int2(s, e);
    }
}

// ---------------- copy hx0 into out column 0 ----------------
__global__ void k_init(const float4* __restrict__ hx4, float* __restrict__ outp)
{
    int i = blockIdx.x * 256 + threadIdx.x;
    int n = i >> 4, q = i & 15;
    ((float4*)(outp + (size_t)n * 256))[q] = hx4[i];
}

// ---------------- aggregation: wave per node ----------------
__global__ __launch_bounds__(256) void k_agg(
    const float* __restrict__ outp, const u16* __restrict__ w,
    const int2* __restrict__ rec, const int* __restrict__ rowstart,
    const float* __restrict__ invdeg, float* __restrict__ agg, int it)
{
    int lane = threadIdx.x & 63;
    int n = blockIdx.x * 4 + (threadIdx.x >> 6);
    n = __builtin_amdgcn_readfirstlane(n);
    int p0 = rowstart[n], p1 = rowstart[n + 1];
    const float* hxcol = outp + (size_t)it * 64 + lane;
    float acc = 0.f;
    for (int p = p0; p < p1; ++p) {
        int2 r = rec[p];
        float hv = hxcol[(size_t)r.x * 256];
        float wv = bf2f(w[(size_t)r.y * 64 + lane]);
        acc = fmaf(hv, wv, acc);
    }
    agg[(size_t)n * 64 + lane] = acc * invdeg[n];
}

// ======== fused GRU: gate GEMM + gi/gh MFMA + inorm + gates, all in-kernel ========
// Wave owns 16 nodes. C/D layout: col=lane&15 (=output feat within tile),
// row=(lane>>4)*4+reg (=node within 16). Stats reduced over the 16-lane t-group.
__global__ __launch_bounds__(256) void k_gru_fused(
    float* __restrict__ outp, const float* __restrict__ agg,
    const u16* __restrict__ wb,
    const float* __restrict__ big, const float* __restrict__ bih,
    const float* __restrict__ bhh, int it)
{
    __shared__ u16 hbuf[4][16 * 68];
    int tid = threadIdx.x;
    int wave = tid >> 6, lane = tid & 63;
    int q = lane >> 4, t = lane & 15;
    int nbase = blockIdx.x * 64 + wave * 16;
    u16* hb = hbuf[wave];
    const u16* wigb = wb;
    const u16* whhb = wb + 4096;
    const u16* wihb = wb + 16384;

    // ---- stage hx -> hb (bf16), coalesced float4 reads ----
    {
        int c = lane & 15;
        int mrow = lane >> 4;
#pragma unroll
        for (int rep = 0; rep < 4; ++rep) {
            int m = rep * 4 + mrow;
            int node = nbase + m;
            float4 v = make_float4(0.f, 0.f, 0.f, 0.f);
            if (node < NN)
                v = *(const float4*)(outp + (size_t)node * 256 + (size_t)it * 64 + c * 4);
            u16* p = &hb[m * 68 + c * 4];
            p[0] = f2bf(v.x); p[1] = f2bf(v.y); p[2] = f2bf(v.z); p[3] = f2bf(v.w);
        }
    }
    // (wave-private buffer; in-order DS pipe makes a barrier unnecessary)

    // ---- hx A-frags + hx in C-layout ----
    s16x8 ahx[2];
    ahx[0] = lds_frag(&hb[t * 68 + q * 8]);
    ahx[1] = lds_frag(&hb[t * 68 + 32 + q * 8]);
    u16 hxc[4][4];
#pragma unroll
    for (int ni = 0; ni < 4; ++ni)
#pragma unroll
        for (int r = 0; r < 4; ++r)
            hxc[ni][r] = hb[(q * 4 + r) * 68 + ni * 16 + t];

    // ---- gate GEMM: sigmoid(hx @ Wig^T + big) * agg -> inp (to hb) ----
#pragma unroll
    for (int ni = 0; ni < 4; ++ni) {
        float bg = big[ni * 16 + t];
        s16x8 b0 = gfrag(wigb, ni * 16 + t, 0, q);
        s16x8 b1 = gfrag(wigb, ni * 16 + t, 1, q);
        f32x4 acc = {bg, bg, bg, bg};
        acc = __builtin_amdgcn_mfma_f32_16x16x32_bf16(ahx[0], b0, acc, 0, 0, 0);
        acc = __builtin_amdgcn_mfma_f32_16x16x32_bf16(ahx[1], b1, acc, 0, 0, 0);
#pragma unroll
        for (int r = 0; r < 4; ++r) {
            int node = nbase + q * 4 + r;
            float av = (node < NN) ? agg[(size_t)node * 64 + ni * 16 + t] : 0.f;
            float iv = sigmoidf_(acc[r]) * av;
            hb[(q * 4 + r) * 68 + ni * 16 + t] = f2bf(iv);
        }
    }

    // ---- gh = hx @ Whh^T  (12 tiles, packed bf16 in regs + stats) ----
    float sgh[4] = {0.f, 0.f, 0.f, 0.f}, qgh[4] = {0.f, 0.f, 0.f, 0.f};
    u32 ghp[12][2];
#pragma unroll
    for (int ni = 0; ni < 12; ++ni) {
        s16x8 b0 = gfrag(whhb, ni * 16 + t, 0, q);
        s16x8 b1 = gfrag(whhb, ni * 16 + t, 1, q);
        f32x4 acc = {0.f, 0.f, 0.f, 0.f};
        acc = __builtin_amdgcn_mfma_f32_16x16x32_bf16(ahx[0], b0, acc, 0, 0, 0);
        acc = __builtin_amdgcn_mfma_f32_16x16x32_bf16(ahx[1], b1, acc, 0, 0, 0);
#pragma unroll
        for (int r = 0; r < 4; ++r) { sgh[r] += acc[r]; qgh[r] += acc[r] * acc[r]; }
        ghp[ni][0] = pack2(acc[0], acc[1]);
        ghp[ni][1] = pack2(acc[2], acc[3]);
    }

    // ---- inp A-frags (after LDS write above; same-wave ordering) ----
    s16x8 ain[2];
    ain[0] = lds_frag(&hb[t * 68 + q * 8]);
    ain[1] = lds_frag(&hb[t * 68 + 32 + q * 8]);

    // ---- gi = inp @ Wih^T ----
    float sgi[4] = {0.f, 0.f, 0.f, 0.f}, qgi[4] = {0.f, 0.f, 0.f, 0.f};
    u32 gip[12][2];
#pragma unroll
    for (int ni = 0; ni < 12; ++ni) {
        s16x8 b0 = gfrag(wihb, ni * 16 + t, 0, q);
        s16x8 b1 = gfrag(wihb, ni * 16 + t, 1, q);
        f32x4 acc = {0.f, 0.f, 0.f, 0.f};
        acc = __builtin_amdgcn_mfma_f32_16x16x32_bf16(ain[0], b0, acc, 0, 0, 0);
        acc = __builtin_amdgcn_mfma_f32_16x16x32_bf16(ain[1], b1, acc, 0, 0, 0);
#pragma unroll
        for (int r = 0; r < 4; ++r) { sgi[r] += acc[r]; qgi[r] += acc[r] * acc[r]; }
        gip[ni][0] = pack2(acc[0], acc[1]);
        gip[ni][1] = pack2(acc[2], acc[3]);
    }

    // ---- reduce stats over t-group (cols of each node live in 16 consecutive lanes) ----
#pragma unroll
    for (int m = 1; m < 16; m <<= 1) {
#pragma unroll
        for (int r = 0; r < 4; ++r) {
            sgh[r] += __shfl_xor(sgh[r], m, 64);
            qgh[r] += __shfl_xor(qgh[r], m, 64);
            sgi[r] += __shfl_xor(sgi[r], m, 64);
            qgi[r] += __shfl_xor(qgi[r], m, 64);
        }
    }
    float mi_[4], ri_[4], mh_[4], rh_[4];
#pragma unroll
    for (int r = 0; r < 4; ++r) {
        mi_[r] = sgi[r] * (1.f / 192.f);
        mh_[r] = sgh[r] * (1.f / 192.f);
        ri_[r] = rsqrtf(qgi[r] * (1.f / 192.f) - mi_[r] * mi_[r] + EPSI);
        rh_[r] = rsqrtf(qgh[r] * (1.f / 192.f) - mh_[r] * mh_[r] + EPSI);
    }

    // ---- gates + hx update + store ----
#pragma unroll
    for (int ni = 0; ni < 4; ++ni) {
        int f = ni * 16 + t;
        float bi_r = bih[f], bi_i = bih[64 + f], bi_n = bih[128 + f];
        float bh_r = bhh[f], bh_i = bhh[64 + f], bh_n = bhh[128 + f];
#pragma unroll
        for (int r = 0; r < 4; ++r) {
            int node = nbase + q * 4 + r;
            float iv_r = (unpk(gip[ni], r) - mi_[r]) * ri_[r];
            float iv_i = (unpk(gip[ni + 4], r) - mi_[r]) * ri_[r];
            float iv_n = (unpk(gip[ni + 8], r) - mi_[r]) * ri_[r];
            float hv_r = (unpk(ghp[ni], r) - mh_[r]) * rh_[r];
            float hv_i = (unpk(ghp[ni + 4], r) - mh_[r]) * rh_[r];
            float hv_n = (unpk(ghp[ni + 8], r) - mh_[r]) * rh_[r];
            float rg = sigmoidf_(iv_r + bi_r + hv_r + bh_r);
            float zg = sigmoidf_(iv_i + bi_i + hv_i + bh_i);
            float ng = tanhf(iv_n + bi_n + rg * (hv_n + bh_n));
            float ho = bf2f(hxc[ni][r]);
            float res = ng + zg * (ho - ng);
            if (node < NN)
                outp[(size_t)node * 256 + (size_t)(it + 1) * 64 + f] = res;
        }
    }
}

extern "C" void kernel_launch(void* const* d_in, const int* in_sizes, int n_in,
                              void* d_out, int out_size, void* d_ws, size_t ws_size,
                              hipStream_t stream)
{
    const float* hx  = (const float*)d_in[0];
    const int*   eix = (const int*)d_in[1];
    const float* ef  = (const float*)d_in[2];
    const float* fW1 = (const float*)d_in[3];
    const float* fb1 = (const float*)d_in[4];
    const float* fW2 = (const float*)d_in[5];
    const float* fb2 = (const float*)d_in[6];
    const float* fW3 = (const float*)d_in[7];
    const float* fb3 = (const float*)d_in[8];
    const float* Wih = (const float*)d_in[9];
    const float* Whh = (const float*)d_in[10];
    const float* bih = (const float*)d_in[11];
    const float* bhh = (const float*)d_in[12];
    const float* Wig = (const float*)d_in[13];
    const float* big = (const float*)d_in[14];
    float* outp = (float*)d_out;
    char* ws = (char*)d_ws;

    u16*    w      = (u16*)(ws + WS_W);
    float*  agg    = (float*)(ws + WS_AGG);
    u16*    wb     = (u16*)(ws + WS_WB);
    float*  invdeg = (float*)(ws + WS_INVDEG);
    int*    counts = (int*)(ws + WS_COUNTS);
    int*    rowst  = (int*)(ws + WS_ROWSTART);
    int*    cursor = (int*)(ws + WS_CURSOR);
    int*    bsum   = (int*)(ws + WS_BSUM);
    int*    bsumex = (int*)(ws + WS_BSUMEX);
    int2*   rec    = (int2*)(ws + WS_REC);

    hipMemsetAsync(counts, 0, NN * sizeof(int), stream);
    k_prep_w<<<112, 256, 0, stream>>>(Wig, Whh, Wih, wb);
    k_fnet_mfma<<<9766, 256, 0, stream>>>(ef, fW1, fb1, fW2, fb2, fW3, fb3, w);
    k_count<<<(NE + 255) / 256, 256, 0, stream>>>(eix, counts);
    k_scan_partial<<<391, 256, 0, stream>>>(counts, bsum);
    k_scan_bsum<<<1, 512, 0, stream>>>(bsum, bsumex);
    k_scan_final<<<391, 256, 0, stream>>>(counts, bsumex, rowst, cursor, invdeg);
    k_scatter<<<(NE + 255) / 256, 256, 0, stream>>>(eix, cursor, rec);
    k_init<<<6250, 256, 0, stream>>>((const float4*)hx, outp);

    for (int it = 0; it < 3; ++it) {
        k_agg<<<25000, 256, 0, stream>>>(outp, w, rec, rowst, invdeg, agg, it);
        k_gru_fused<<<1563, 256, 0, stream>>>(outp, agg, wb, big, bih, bhh, it);
    }
}